// Round 11
// baseline (252.295 us; speedup 1.0000x reference)
//
#include <hip/hip_runtime.h>
#include <hip/hip_bf16.h>
#include <math.h>

#define NNODES 10000
#define NEDGES 80000
#define FDIM   1024
#define BGR    32
#define LLEN   800
#define CCH    16
#define DDIM   128
#define NPAD2  10240   // 40 * 256
#define NE_BLK 625     // 2*NEDGES/256

typedef __attribute__((ext_vector_type(4))) _Float16 f16x4;
typedef __attribute__((ext_vector_type(8))) _Float16 f16x8;
typedef __attribute__((ext_vector_type(4))) float f32x4;

__device__ __forceinline__ float lrelu(float v){ return v > 0.0f ? v : 0.01f*v; }

// gather one node: lt in [0,128), f = lt*8
__device__ __forceinline__ void gather_body(int n, int br, int lt,
    const _Float16* __restrict__ xs_, const int* __restrict__ rowstart_,
    const int* __restrict__ csr_, const float* __restrict__ dinv_,
    _Float16* __restrict__ xa_)
{
  const _Float16* xs = xs_ + (size_t)br*NNODES*FDIM;
  const int* rowstart = rowstart_ + br*(NNODES+1);
  const int* csr = csr_ + br*NEDGES;
  const float* dinv = dinv_ + br*NNODES;
  _Float16* xa = xa_ + (size_t)br*NPAD2*FDIM;

  const int f = lt*8;
  _Float16* op = xa + (size_t)n*FDIM + f;
  if (n >= NNODES){
    f16x8 z = {};
    *(f16x8*)op = z;
    return;
  }
  const int s0 = rowstart[n], s1 = rowstart[n+1];
  f16x8 sv = *(const f16x8*)(xs + (size_t)n*FDIM + f);
  float a0=sv[0],a1=sv[1],a2=sv[2],a3=sv[3],a4=sv[4],a5=sv[5],a6=sv[6],a7=sv[7];
  int i = s0;
  for (; i + 4 <= s1; i += 4){
    const int r0 = csr[i], r1 = csr[i+1], r2 = csr[i+2], r3 = csr[i+3];
    f16x8 v0 = *(const f16x8*)(xs + (size_t)r0*FDIM + f);
    f16x8 v1 = *(const f16x8*)(xs + (size_t)r1*FDIM + f);
    f16x8 v2 = *(const f16x8*)(xs + (size_t)r2*FDIM + f);
    f16x8 v3 = *(const f16x8*)(xs + (size_t)r3*FDIM + f);
    a0 += (float)v0[0]+(float)v1[0]+(float)v2[0]+(float)v3[0];
    a1 += (float)v0[1]+(float)v1[1]+(float)v2[1]+(float)v3[1];
    a2 += (float)v0[2]+(float)v1[2]+(float)v2[2]+(float)v3[2];
    a3 += (float)v0[3]+(float)v1[3]+(float)v2[3]+(float)v3[3];
    a4 += (float)v0[4]+(float)v1[4]+(float)v2[4]+(float)v3[4];
    a5 += (float)v0[5]+(float)v1[5]+(float)v2[5]+(float)v3[5];
    a6 += (float)v0[6]+(float)v1[6]+(float)v2[6]+(float)v3[6];
    a7 += (float)v0[7]+(float)v1[7]+(float)v2[7]+(float)v3[7];
  }
  for (; i < s1; ++i){
    const int r = csr[i];
    f16x8 v = *(const f16x8*)(xs + (size_t)r*FDIM + f);
    a0+=(float)v[0]; a1+=(float)v[1]; a2+=(float)v[2]; a3+=(float)v[3];
    a4+=(float)v[4]; a5+=(float)v[5]; a6+=(float)v[6]; a7+=(float)v[7];
  }
  const float d = dinv[n];
  f16x8 o;
  o[0]=(_Float16)(a0*d); o[1]=(_Float16)(a1*d); o[2]=(_Float16)(a2*d); o[3]=(_Float16)(a3*d);
  o[4]=(_Float16)(a4*d); o[5]=(_Float16)(a5*d); o[6]=(_Float16)(a6*d); o[7]=(_Float16)(a7*d);
  *(f16x8*)op = o;
}

// misc1: edgedeg (both) || W transpose+cast (both) || masif (both). grid 2737, blk 256
__global__ __launch_bounds__(256) void k_misc1(const int* __restrict__ ei0, const int* __restrict__ ei1,
                                               int* __restrict__ cnt,
                                               const float* __restrict__ W0, const float* __restrict__ W1,
                                               _Float16* __restrict__ Wt,
                                               const float* __restrict__ ms1, const float* __restrict__ mf1,
                                               const float* __restrict__ ms2, const float* __restrict__ mf2,
                                               const float* __restrict__ sw1, const float* __restrict__ sb1,
                                               const float* __restrict__ fw1, const float* __restrict__ fb1,
                                               const float* __restrict__ sw2, const float* __restrict__ sb2,
                                               const float* __restrict__ fw2, const float* __restrict__ fb2,
                                               const float* __restrict__ Wm1, const float* __restrict__ bm1,
                                               const float* __restrict__ Wm2, const float* __restrict__ bm2,
                                               float* __restrict__ m12){
  __shared__ float tl[32][33];
  __shared__ float sf[LLEN];
  __shared__ float w80[80];
  const int bx = blockIdx.x, t = threadIdx.x;
  if (bx < NE_BLK){
    int i = bx*256 + t;
    int br = i >= NEDGES;
    int e  = br ? i - NEDGES : i;
    const int* ei = br ? ei1 : ei0;
    atomicAdd(&cnt[br*NNODES + ei[NEDGES + e]], 1);
  } else if (bx < NE_BLK + 2048){
    const int idx = bx - NE_BLK;
    const int br = idx >> 10, tile = idx & 1023;
    const float* W = br ? W1 : W0;
    _Float16* Wo = Wt + (size_t)br*FDIM*FDIM;
    const int k0 = (tile >> 5)*32, n0 = (tile & 31)*32;
    const int r = t >> 3, c4 = (t & 7)*4;
    const float4 v = *(const float4*)(W + (size_t)(k0+r)*FDIM + n0 + c4);
    tl[r][c4] = v.x; tl[r][c4+1] = v.y; tl[r][c4+2] = v.z; tl[r][c4+3] = v.w;
    __syncthreads();
    f16x4 o;
    o[0]=(_Float16)tl[c4  ][r];
    o[1]=(_Float16)tl[c4+1][r];
    o[2]=(_Float16)tl[c4+2][r];
    o[3]=(_Float16)tl[c4+3][r];
    *(f16x4*)(Wo + (size_t)(n0+r)*FDIM + k0 + c4) = o;
  } else {
    const int idx = bx - NE_BLK - 2048;   // 0..63
    const int br = idx >> 5, b = idx & 31;
    const float* ms = br ? ms2 : ms1;
    const float* mf = br ? mf2 : mf1;
    const float swv = (br ? sw2 : sw1)[0], sbv = (br ? sb2 : sb1)[0];
    const float fwv = (br ? fw2 : fw1)[0], fbv = (br ? fb2 : fb1)[0];
    const float* Wm = br ? Wm2 : Wm1;
    const float* bm = br ? bm2 : bm1;
    for (int l = t; l < LLEN; l += 256){
      float sm = 0.f, fm = 0.f;
      for (int c = 0; c < CCH; ++c){
        sm += ms[((size_t)b*CCH + c)*LLEN + l];
        fm += mf[((size_t)b*CCH + c)*LLEN + l];
      }
      sm = fmaxf(sm*(1.0f/16.0f)*swv + sbv, 0.f);
      fm = fmaxf(fm*(1.0f/16.0f)*fwv + fbv, 0.f);
      sf[l] = sm + fm;
    }
    __syncthreads();
    if (t < 80){
      float a = 0.f;
      for (int j = 0; j < 10; ++j) a += sf[t*10 + j];
      w80[t] = a * 0.05f;
    }
    __syncthreads();
    if (t < 64){
      float acc = bm[t];
      for (int k = 0; k < 80; ++k) acc += w80[k] * Wm[k*64 + t];
      m12[((size_t)br*BGR + b)*64 + t] = acc;
    }
  }
}

// per-branch exclusive scan + dinv + bstart; grid=2 blocks of 1024
__global__ __launch_bounds__(1024) void k_scan(const int* __restrict__ cnt, int* __restrict__ rowstart,
                                               float* __restrict__ dinv,
                                               const int* __restrict__ batch0,
                                               const int* __restrict__ batch1,
                                               int* __restrict__ bstart_){
  __shared__ int part[1024];
  const int br = blockIdx.x;
  const int* c = cnt + br*NNODES;
  int* rs = rowstart + br*(NNODES+1);
  float* dv = dinv + br*NNODES;
  const int* batch = br ? batch1 : batch0;
  int* bstart = bstart_ + br*(BGR+1);
  const int t = threadIdx.x;
  const int base = t*10;
  int local[10];
  int s = 0;
  #pragma unroll
  for (int i = 0; i < 10; ++i){
    int v = (base+i < NNODES) ? c[base+i] : 0;
    local[i] = s; s += v;
    if (base+i < NNODES) dv[base+i] = rsqrtf((float)v + 1.0f);
  }
  part[t] = s;
  __syncthreads();
  for (int off = 1; off < 1024; off <<= 1){
    int v = (t >= off) ? part[t-off] : 0;
    __syncthreads();
    part[t] += v;
    __syncthreads();
  }
  const int prev = (t == 0) ? 0 : part[t-1];
  #pragma unroll
  for (int i = 0; i < 10; ++i)
    if (base+i < NNODES) rs[base+i] = prev + local[i];
  if (t == 0) rs[NNODES] = NEDGES;
  for (int i = base; i < base+10 && i < NNODES; ++i){
    int b = batch[i];
    if (i == 0){ for (int bb = 0; bb <= b; ++bb) bstart[bb] = 0; }
    else {
      int pb = batch[i-1];
      if (b != pb) for (int bb = pb+1; bb <= b; ++bb) bstart[bb] = i;
    }
    if (i == NNODES-1){ for (int bb = b+1; bb <= BGR; ++bb) bstart[bb] = NNODES; }
  }
}

// misc2: CSR fill (both) || cvtX (both). grid 625+20000, blk 256
__global__ __launch_bounds__(256) void k_misc2(const int* __restrict__ ei0, const int* __restrict__ ei1,
                                               const int* __restrict__ rowstart,
                                               int* __restrict__ cursor, int* __restrict__ csr,
                                               const float* __restrict__ x0, const float* __restrict__ x1,
                                               const float* __restrict__ dinv,
                                               _Float16* __restrict__ xs){
  const int bx = blockIdx.x, t = threadIdx.x;
  if (bx < NE_BLK){
    int i = bx*256 + t;
    int br = i >= NEDGES;
    int e  = br ? i - NEDGES : i;
    const int* ei = br ? ei1 : ei0;
    int r = ei[e], c = ei[NEDGES + e];
    int pos = atomicAdd(&cursor[br*NNODES + c], 1);
    csr[br*NEDGES + rowstart[br*(NNODES+1) + c] + pos] = r;
  } else {
    const int idx = bx - NE_BLK;              // 0..19999
    const int br = idx >= NNODES;
    const int row = br ? idx - NNODES : idx;
    const float* x = (br ? x1 : x0) + (size_t)row*FDIM;
    _Float16* o = xs + ((size_t)br*NNODES + row)*FDIM;
    const int f = t*4;
    const float d = dinv[br*NNODES + row];
    const float4 v = *(const float4*)(x + f);
    f16x4 ov;
    ov[0]=(_Float16)(v.x*d); ov[1]=(_Float16)(v.y*d); ov[2]=(_Float16)(v.z*d); ov[3]=(_Float16)(v.w*d);
    *(f16x4*)(o + f) = ov;
  }
}

// gather both branches: grid (NPAD2/2, 2), blk 256 (2 nodes/block)
__global__ __launch_bounds__(256) void k_gath(const _Float16* __restrict__ xs,
                                              const int* __restrict__ rowstart,
                                              const int* __restrict__ csr,
                                              const float* __restrict__ dinv,
                                              _Float16* __restrict__ xa){
  const int t = threadIdx.x;
  const int n = blockIdx.x*2 + (t >> 7);
  gather_body(n, blockIdx.y, t & 127, xs, rowstart, csr, dinv, xa);
}

// hh = lrelu(xa @ W + b), f16 out; BOTH branches, grid 320 blocks x 512 thr.
// 256x256 tile, BK=32, 8 waves (2M x 4N), 64KB LDS double-buffer.
// R7-proven schedule: stage(next) -> vmcnt(4) -> barrier -> compute -> barrier.
// XOR swizzle slot ^= (row>>1)&3 on global source + ds_read (both-sides rule).
// XCD-local bijection (320 = 8*40): each XCD owns 10 row-panels x 4 cols ->
// B (2MB/branch) L2-resident, each A panel fetched ~once.
__global__ __launch_bounds__(512) void k_gemm256(const _Float16* __restrict__ A_,
                                                 const _Float16* __restrict__ Bt_,
                                                 const float* __restrict__ bg0,
                                                 const float* __restrict__ bg1,
                                                 _Float16* __restrict__ hh_){
  __shared__ _Float16 As[2][256*32];
  __shared__ _Float16 Bs[2][256*32];

  const int id = blockIdx.x;                  // 0..319
  const int w  = (id & 7)*40 + (id >> 3);     // XCD-local bijection
  const int br  = (w >= 160) ? 1 : 0;
  const int rem = w - br*160;
  const int row = rem >> 2;                   // 0..39
  const int col = rem & 3;                    // 0..3

  const _Float16* A  = A_  + (size_t)br*NPAD2*FDIM;
  const _Float16* Bt = Bt_ + (size_t)br*FDIM*FDIM;
  const float* bg = br ? bg1 : bg0;
  _Float16* hh = hh_ + (size_t)br*NPAD2*FDIM;

  const int row0 = row*256, col0 = col*256;
  const int tid  = threadIdx.x;
  const int lane = tid & 63, wid = tid >> 6;   // 8 waves
  const int wm = wid >> 2, wn = wid & 3;       // 2 x 4

  // staging geometry: per thread 2 gloads per matrix; load j covers rows j*128..
  // lane l: row = wid*16 + (l>>2) (+ j*128), LDS dest = wave-base + l*16 (linear).
  const int rsta = wid*16 + (lane >> 2);
  const int gs   = ((lane & 3) ^ ((lane >> 3) & 3)) * 8;   // pre-swizzled slot (f16 units)
  const _Float16* gA0 = A  + (size_t)(row0 + rsta)*FDIM + gs;
  const _Float16* gA1 = gA0 + (size_t)128*FDIM;
  const _Float16* gB0 = Bt + (size_t)(col0 + rsta)*FDIM + gs;
  const _Float16* gB1 = gB0 + (size_t)128*FDIM;
  const int dst0 = (wid*16)*32;          // f16 index of wave base, j=0
  const int dst1 = (128 + wid*16)*32;    // j=1

  f32x4 acc[8][4] = {};

  auto stage = [&](int buf, int k0){
    __builtin_amdgcn_global_load_lds(
      (const __attribute__((address_space(1))) void*)(gA0 + k0),
      (__attribute__((address_space(3))) void*)(&As[buf][dst0]), 16, 0, 0);
    __builtin_amdgcn_global_load_lds(
      (const __attribute__((address_space(1))) void*)(gB0 + k0),
      (__attribute__((address_space(3))) void*)(&Bs[buf][dst0]), 16, 0, 0);
    __builtin_amdgcn_global_load_lds(
      (const __attribute__((address_space(1))) void*)(gA1 + k0),
      (__attribute__((address_space(3))) void*)(&As[buf][dst1]), 16, 0, 0);
    __builtin_amdgcn_global_load_lds(
      (const __attribute__((address_space(1))) void*)(gB1 + k0),
      (__attribute__((address_space(3))) void*)(&Bs[buf][dst1]), 16, 0, 0);
  };

  auto compute = [&](int buf){
    f16x8 af[8], bf[4];
    const int s = lane >> 4;     // k-slot 0..3
    #pragma unroll
    for (int i = 0; i < 8; ++i){
      const int rA = wm*128 + i*16 + (lane & 15);
      af[i] = *(const f16x8*)(&As[buf][rA*32 + (s ^ ((rA >> 1) & 3))*8]);
    }
    #pragma unroll
    for (int i = 0; i < 4; ++i){
      const int rB = wn*64 + i*16 + (lane & 15);
      bf[i] = *(const f16x8*)(&Bs[buf][rB*32 + (s ^ ((rB >> 1) & 3))*8]);
    }
    #pragma unroll
    for (int mi = 0; mi < 8; ++mi)
      #pragma unroll
      for (int ni = 0; ni < 4; ++ni)
        acc[mi][ni] = __builtin_amdgcn_mfma_f32_16x16x32_f16(af[mi], bf[ni], acc[mi][ni], 0, 0, 0);
  };

  stage(0, 0);                                  // 4 loads in flight
  #pragma unroll 2
  for (int t = 0; t < 32; ++t){
    if (t < 31){
      stage((t+1) & 1, (t+1)*32);               // +4 -> 8 in flight
      asm volatile("s_waitcnt vmcnt(4)" ::: "memory");   // tile t landed
    } else {
      asm volatile("s_waitcnt vmcnt(0)" ::: "memory");
    }
    __builtin_amdgcn_s_barrier();               // next tile's loads stay in flight
    compute(t & 1);
    __builtin_amdgcn_s_barrier();               // all reads done before overwrite
  }

  float bcol[4];
  #pragma unroll
  for (int ni = 0; ni < 4; ++ni) bcol[ni] = bg[col0 + wn*64 + ni*16 + (lane & 15)];
  #pragma unroll
  for (int mi = 0; mi < 8; ++mi){
    #pragma unroll
    for (int j = 0; j < 4; ++j){
      const int grow = row0 + wm*128 + mi*16 + (lane >> 4)*4 + j;
      _Float16* hr = hh + (size_t)grow*FDIM + col0 + wn*64 + (lane & 15);
      #pragma unroll
      for (int ni = 0; ni < 4; ++ni) hr[ni*16] = (_Float16)lrelu(acc[mi][ni][j] + bcol[ni]);
    }
  }
}

// pool[br][b][col] = mean over rows; grid (4, 32, 2), blk 256
__global__ __launch_bounds__(256) void k_pool(const _Float16* __restrict__ hh_,
                                              const int* __restrict__ bstart_,
                                              float* __restrict__ pool_){
  const int br = blockIdx.z;
  const _Float16* hh = hh_ + (size_t)br*NPAD2*FDIM;
  const int* bstart = bstart_ + br*(BGR+1);
  float* pool = pool_ + br*BGR*FDIM;
  const int b = blockIdx.y;
  const int col = blockIdx.x*256 + threadIdx.x;
  const int s0 = bstart[b], s1 = bstart[b+1];
  float sum = 0.f;
  int n = s0;
  for (; n + 4 <= s1; n += 4){
    float h0 = (float)hh[(size_t)(n  )*FDIM + col];
    float h1 = (float)hh[(size_t)(n+1)*FDIM + col];
    float h2 = (float)hh[(size_t)(n+2)*FDIM + col];
    float h3 = (float)hh[(size_t)(n+3)*FDIM + col];
    sum += (h0+h1)+(h2+h3);
  }
  for (; n < s1; ++n) sum += (float)hh[(size_t)n*FDIM + col];
  const float inv = 1.0f / fmaxf((float)(s1 - s0), 1.0f);
  pool[b*FDIM + col] = sum * inv;
}

// fused pf GEMV; grid (32,2), blk 512
__global__ __launch_bounds__(512) void k_pf(const float* __restrict__ pool_,
                                            const float* __restrict__ W0,
                                            const float* __restrict__ W1,
                                            const float* __restrict__ bias0,
                                            const float* __restrict__ bias1,
                                            float* __restrict__ x12){
  __shared__ float red[512];
  const int br = blockIdx.y, b = blockIdx.x, t = threadIdx.x;
  const int d = t & 127, kq = t >> 7;
  const float* W = (br ? W1 : W0) + (size_t)kq*256*DDIM + d;
  const float* pp = pool_ + (size_t)(br*BGR + b)*FDIM + kq*256;
  float acc = 0.f;
  #pragma unroll 4
  for (int kk = 0; kk < 256; kk += 4){
    const float4 pv = *(const float4*)(pp + kk);
    acc += pv.x * W[(kk  )*DDIM] + pv.y * W[(kk+1)*DDIM]
         + pv.z * W[(kk+2)*DDIM] + pv.w * W[(kk+3)*DDIM];
  }
  red[t] = acc;
  __syncthreads();
  if (t < 128){
    float a = red[t] + red[t+128] + red[t+256] + red[t+384] + (br ? bias1 : bias0)[t];
    x12[((size_t)br*BGR + b)*DDIM + t] = lrelu(a);
  }
}

// head: fc1 -> fc2 -> final sigmoid; grid 32, blk 256
__global__ __launch_bounds__(256) void k_head(const float* __restrict__ x12,
                                              const float* __restrict__ Wfc1, const float* __restrict__ bfc1,
                                              const float* __restrict__ Wfc2, const float* __restrict__ bfc2,
                                              const float* __restrict__ m12,
                                              const float* __restrict__ Wout, const float* __restrict__ bout,
                                              float* __restrict__ out){
  __shared__ float xf[256];
  __shared__ float xc[64];
  __shared__ float red[192];
  const int b = blockIdx.x, t = threadIdx.x;
  const float* xin1 = x12 + (size_t)b*DDIM;
  const float* xin2 = x12 + (size_t)(BGR + b)*DDIM;
  float acc = bfc1[t];
  for (int k = 0; k < 128; ++k) acc += xin1[k] * Wfc1[k*256 + t];
  for (int k = 0; k < 128; ++k) acc += xin2[k] * Wfc1[(128+k)*256 + t];
  xf[t] = lrelu(acc);
  __syncthreads();
  if (t < 64){
    float a = bfc2[t];
    for (int k = 0; k < 256; ++k) a += xf[k] * Wfc2[k*64 + t];
    xc[t] = lrelu(a);
  }
  __syncthreads();
  if (t < 192){
    float v;
    if (t < 64)       v = xc[t] * Wout[t];
    else if (t < 128) v = m12[(size_t)b*64 + (t-64)] * Wout[t];
    else              v = m12[(size_t)(BGR + b)*64 + (t-128)] * Wout[t];
    red[t] = v;
  }
  __syncthreads();
  if (t == 0){
    float a = bout[0];
    for (int i = 0; i < 192; ++i) a += red[i];
    out[b] = 1.0f / (1.0f + expf(-a));
  }
}

extern "C" void kernel_launch(void* const* d_in, const int* in_sizes, int n_in,
                              void* d_out, int out_size, void* d_ws, size_t ws_size,
                              hipStream_t stream){
  const float* pro1_x = (const float*)d_in[0];
  const int*   ei1    = (const int*)d_in[1];
  const int*   batch1 = (const int*)d_in[2];
  const float* pro2_x = (const float*)d_in[3];
  const int*   ei2    = (const int*)d_in[4];
  const int*   batch2 = (const int*)d_in[5];
  const float* mas1_s = (const float*)d_in[6];
  const float* mas1_f = (const float*)d_in[7];
  const float* mas2_s = (const float*)d_in[8];
  const float* mas2_f = (const float*)d_in[9];
  const float* W_g1 = (const float*)d_in[10]; const float* b_g1 = (const float*)d_in[11];
  const float* W_g2 = (const float*)d_in[12]; const float* b_g2 = (const float*)d_in[13];
  const float* W_pf1= (const float*)d_in[14]; const float* b_pf1= (const float*)d_in[15];
  const float* W_pf2= (const float*)d_in[16]; const float* b_pf2= (const float*)d_in[17];
  const float* W_fc1= (const float*)d_in[18]; const float* b_fc1= (const float*)d_in[19];
  const float* W_fc2= (const float*)d_in[20]; const float* b_fc2= (const float*)d_in[21];
  const float* cs1w = (const float*)d_in[22]; const float* cs1b = (const float*)d_in[23];
  const float* cf1w = (const float*)d_in[24]; const float* cf1b = (const float*)d_in[25];
  const float* cs2w = (const float*)d_in[26]; const float* cs2b = (const float*)d_in[27];
  const float* cf2w = (const float*)d_in[28]; const float* cf2b = (const float*)d_in[29];
  const float* W_m1 = (const float*)d_in[30]; const float* b_m1 = (const float*)d_in[31];
  const float* W_m2 = (const float*)d_in[32]; const float* b_m2 = (const float*)d_in[33];
  const float* W_out= (const float*)d_in[34]; const float* b_out= (const float*)d_in[35];
  float* out = (float*)d_out;
  (void)in_sizes; (void)n_in; (void)out_size; (void)ws_size;

  char* p = (char*)d_ws;
  auto alloc = [&](size_t bytes)->char*{ char* r = p; p += (bytes + 255) & ~(size_t)255; return r; };
  _Float16* xs  = (_Float16*)alloc((size_t)2*NNODES*FDIM*2);
  _Float16* xa  = (_Float16*)alloc((size_t)2*NPAD2*FDIM*2);
  _Float16* Wtb = (_Float16*)alloc((size_t)2*FDIM*FDIM*2);
  _Float16* hh  = (_Float16*)alloc((size_t)2*NPAD2*FDIM*2);
  float* dinv = (float*)alloc((size_t)2*NNODES*4);
  int*   cntcur = (int*)alloc((size_t)4*NNODES*4);
  int*   cnt    = cntcur;
  int*   cursor = cntcur + 2*NNODES;
  int*   rowstart = (int*)alloc((size_t)2*(NNODES+1)*4);
  int*   csr  = (int*)alloc((size_t)2*NEDGES*4);
  int*   bstart = (int*)alloc((size_t)2*(BGR+1)*4);
  float* pool = (float*)alloc((size_t)2*BGR*FDIM*4);
  float* x12  = (float*)alloc((size_t)2*BGR*DDIM*4);
  float* m12  = (float*)alloc((size_t)2*BGR*64*4);

  hipMemsetAsync(cntcur, 0, (size_t)4*NNODES*4, stream);
  k_misc1<<<NE_BLK + 2048 + 64, 256, 0, stream>>>(ei1, ei2, cnt, W_g1, W_g2, Wtb,
                                                  mas1_s, mas1_f, mas2_s, mas2_f,
                                                  cs1w, cs1b, cf1w, cf1b,
                                                  cs2w, cs2b, cf2w, cf2b,
                                                  W_m1, b_m1, W_m2, b_m2, m12);
  k_scan<<<2, 1024, 0, stream>>>(cnt, rowstart, dinv, batch1, batch2, bstart);
  k_misc2<<<NE_BLK + 2*NNODES, 256, 0, stream>>>(ei1, ei2, rowstart, cursor, csr,
                                                 pro1_x, pro2_x, dinv, xs);
  k_gath<<<dim3(NPAD2/2, 2), 256, 0, stream>>>(xs, rowstart, csr, dinv, xa);
  k_gemm256<<<320, 512, 0, stream>>>(xa, Wtb, b_g1, b_g2, hh);
  k_pool<<<dim3(FDIM/256, BGR, 2), 256, 0, stream>>>(hh, bstart, pool);
  k_pf<<<dim3(BGR, 2), 512, 0, stream>>>(pool, W_pf1, W_pf2, b_pf1, b_pf2, x12);
  k_head<<<BGR, 256, 0, stream>>>(x12, W_fc1, b_fc1, W_fc2, b_fc2, m12, W_out, b_out, out);
}

// Round 12
// 195.447 us; speedup vs baseline: 1.2909x; 1.2909x over previous
//
#include <hip/hip_runtime.h>
#include <hip/hip_bf16.h>
#include <math.h>

#define NNODES 10000
#define NEDGES 80000
#define FDIM   1024
#define BGR    32
#define LLEN   800
#define CCH    16
#define DDIM   128
#define NPAD2  10240   // 80 * 128
#define NE_BLK 625     // 2*NEDGES/256

typedef __attribute__((ext_vector_type(4))) _Float16 f16x4;
typedef __attribute__((ext_vector_type(8))) _Float16 f16x8;
typedef __attribute__((ext_vector_type(4))) float f32x4;

__device__ __forceinline__ float lrelu(float v){ return v > 0.0f ? v : 0.01f*v; }

// gather one node: lt in [0,128), f = lt*8
__device__ __forceinline__ void gather_body(int n, int br, int lt,
    const _Float16* __restrict__ xs_, const int* __restrict__ rowstart_,
    const int* __restrict__ csr_, const float* __restrict__ dinv_,
    _Float16* __restrict__ xa_)
{
  const _Float16* xs = xs_ + (size_t)br*NNODES*FDIM;
  const int* rowstart = rowstart_ + br*(NNODES+1);
  const int* csr = csr_ + br*NEDGES;
  const float* dinv = dinv_ + br*NNODES;
  _Float16* xa = xa_ + (size_t)br*NPAD2*FDIM;

  const int f = lt*8;
  _Float16* op = xa + (size_t)n*FDIM + f;
  if (n >= NNODES){
    f16x8 z = {};
    *(f16x8*)op = z;
    return;
  }
  const int s0 = rowstart[n], s1 = rowstart[n+1];
  f16x8 sv = *(const f16x8*)(xs + (size_t)n*FDIM + f);
  float a0=sv[0],a1=sv[1],a2=sv[2],a3=sv[3],a4=sv[4],a5=sv[5],a6=sv[6],a7=sv[7];
  int i = s0;
  for (; i + 4 <= s1; i += 4){
    const int r0 = csr[i], r1 = csr[i+1], r2 = csr[i+2], r3 = csr[i+3];
    f16x8 v0 = *(const f16x8*)(xs + (size_t)r0*FDIM + f);
    f16x8 v1 = *(const f16x8*)(xs + (size_t)r1*FDIM + f);
    f16x8 v2 = *(const f16x8*)(xs + (size_t)r2*FDIM + f);
    f16x8 v3 = *(const f16x8*)(xs + (size_t)r3*FDIM + f);
    a0 += (float)v0[0]+(float)v1[0]+(float)v2[0]+(float)v3[0];
    a1 += (float)v0[1]+(float)v1[1]+(float)v2[1]+(float)v3[1];
    a2 += (float)v0[2]+(float)v1[2]+(float)v2[2]+(float)v3[2];
    a3 += (float)v0[3]+(float)v1[3]+(float)v2[3]+(float)v3[3];
    a4 += (float)v0[4]+(float)v1[4]+(float)v2[4]+(float)v3[4];
    a5 += (float)v0[5]+(float)v1[5]+(float)v2[5]+(float)v3[5];
    a6 += (float)v0[6]+(float)v1[6]+(float)v2[6]+(float)v3[6];
    a7 += (float)v0[7]+(float)v1[7]+(float)v2[7]+(float)v3[7];
  }
  for (; i < s1; ++i){
    const int r = csr[i];
    f16x8 v = *(const f16x8*)(xs + (size_t)r*FDIM + f);
    a0+=(float)v[0]; a1+=(float)v[1]; a2+=(float)v[2]; a3+=(float)v[3];
    a4+=(float)v[4]; a5+=(float)v[5]; a6+=(float)v[6]; a7+=(float)v[7];
  }
  const float d = dinv[n];
  f16x8 o;
  o[0]=(_Float16)(a0*d); o[1]=(_Float16)(a1*d); o[2]=(_Float16)(a2*d); o[3]=(_Float16)(a3*d);
  o[4]=(_Float16)(a4*d); o[5]=(_Float16)(a5*d); o[6]=(_Float16)(a6*d); o[7]=(_Float16)(a7*d);
  *(f16x8*)op = o;
}

// misc1: edgedeg (both) || W transpose+cast (both) || masif (both). grid 2737, blk 256
__global__ __launch_bounds__(256) void k_misc1(const int* __restrict__ ei0, const int* __restrict__ ei1,
                                               int* __restrict__ cnt,
                                               const float* __restrict__ W0, const float* __restrict__ W1,
                                               _Float16* __restrict__ Wt,
                                               const float* __restrict__ ms1, const float* __restrict__ mf1,
                                               const float* __restrict__ ms2, const float* __restrict__ mf2,
                                               const float* __restrict__ sw1, const float* __restrict__ sb1,
                                               const float* __restrict__ fw1, const float* __restrict__ fb1,
                                               const float* __restrict__ sw2, const float* __restrict__ sb2,
                                               const float* __restrict__ fw2, const float* __restrict__ fb2,
                                               const float* __restrict__ Wm1, const float* __restrict__ bm1,
                                               const float* __restrict__ Wm2, const float* __restrict__ bm2,
                                               float* __restrict__ m12){
  __shared__ float tl[32][33];
  __shared__ float sf[LLEN];
  __shared__ float w80[80];
  const int bx = blockIdx.x, t = threadIdx.x;
  if (bx < NE_BLK){
    int i = bx*256 + t;
    int br = i >= NEDGES;
    int e  = br ? i - NEDGES : i;
    const int* ei = br ? ei1 : ei0;
    atomicAdd(&cnt[br*NNODES + ei[NEDGES + e]], 1);
  } else if (bx < NE_BLK + 2048){
    const int idx = bx - NE_BLK;
    const int br = idx >> 10, tile = idx & 1023;
    const float* W = br ? W1 : W0;
    _Float16* Wo = Wt + (size_t)br*FDIM*FDIM;
    const int k0 = (tile >> 5)*32, n0 = (tile & 31)*32;
    const int r = t >> 3, c4 = (t & 7)*4;
    const float4 v = *(const float4*)(W + (size_t)(k0+r)*FDIM + n0 + c4);
    tl[r][c4] = v.x; tl[r][c4+1] = v.y; tl[r][c4+2] = v.z; tl[r][c4+3] = v.w;
    __syncthreads();
    f16x4 o;
    o[0]=(_Float16)tl[c4  ][r];
    o[1]=(_Float16)tl[c4+1][r];
    o[2]=(_Float16)tl[c4+2][r];
    o[3]=(_Float16)tl[c4+3][r];
    *(f16x4*)(Wo + (size_t)(n0+r)*FDIM + k0 + c4) = o;
  } else {
    const int idx = bx - NE_BLK - 2048;   // 0..63
    const int br = idx >> 5, b = idx & 31;
    const float* ms = br ? ms2 : ms1;
    const float* mf = br ? mf2 : mf1;
    const float swv = (br ? sw2 : sw1)[0], sbv = (br ? sb2 : sb1)[0];
    const float fwv = (br ? fw2 : fw1)[0], fbv = (br ? fb2 : fb1)[0];
    const float* Wm = br ? Wm2 : Wm1;
    const float* bm = br ? bm2 : bm1;
    for (int l = t; l < LLEN; l += 256){
      float sm = 0.f, fm = 0.f;
      for (int c = 0; c < CCH; ++c){
        sm += ms[((size_t)b*CCH + c)*LLEN + l];
        fm += mf[((size_t)b*CCH + c)*LLEN + l];
      }
      sm = fmaxf(sm*(1.0f/16.0f)*swv + sbv, 0.f);
      fm = fmaxf(fm*(1.0f/16.0f)*fwv + fbv, 0.f);
      sf[l] = sm + fm;
    }
    __syncthreads();
    if (t < 80){
      float a = 0.f;
      for (int j = 0; j < 10; ++j) a += sf[t*10 + j];
      w80[t] = a * 0.05f;
    }
    __syncthreads();
    if (t < 64){
      float acc = bm[t];
      for (int k = 0; k < 80; ++k) acc += w80[k] * Wm[k*64 + t];
      m12[((size_t)br*BGR + b)*64 + t] = acc;
    }
  }
}

// per-branch exclusive scan + dinv + bstart; grid=2 blocks of 1024
__global__ __launch_bounds__(1024) void k_scan(const int* __restrict__ cnt, int* __restrict__ rowstart,
                                               float* __restrict__ dinv,
                                               const int* __restrict__ batch0,
                                               const int* __restrict__ batch1,
                                               int* __restrict__ bstart_){
  __shared__ int part[1024];
  const int br = blockIdx.x;
  const int* c = cnt + br*NNODES;
  int* rs = rowstart + br*(NNODES+1);
  float* dv = dinv + br*NNODES;
  const int* batch = br ? batch1 : batch0;
  int* bstart = bstart_ + br*(BGR+1);
  const int t = threadIdx.x;
  const int base = t*10;
  int local[10];
  int s = 0;
  #pragma unroll
  for (int i = 0; i < 10; ++i){
    int v = (base+i < NNODES) ? c[base+i] : 0;
    local[i] = s; s += v;
    if (base+i < NNODES) dv[base+i] = rsqrtf((float)v + 1.0f);
  }
  part[t] = s;
  __syncthreads();
  for (int off = 1; off < 1024; off <<= 1){
    int v = (t >= off) ? part[t-off] : 0;
    __syncthreads();
    part[t] += v;
    __syncthreads();
  }
  const int prev = (t == 0) ? 0 : part[t-1];
  #pragma unroll
  for (int i = 0; i < 10; ++i)
    if (base+i < NNODES) rs[base+i] = prev + local[i];
  if (t == 0) rs[NNODES] = NEDGES;
  for (int i = base; i < base+10 && i < NNODES; ++i){
    int b = batch[i];
    if (i == 0){ for (int bb = 0; bb <= b; ++bb) bstart[bb] = 0; }
    else {
      int pb = batch[i-1];
      if (b != pb) for (int bb = pb+1; bb <= b; ++bb) bstart[bb] = i;
    }
    if (i == NNODES-1){ for (int bb = b+1; bb <= BGR; ++bb) bstart[bb] = NNODES; }
  }
}

// misc2: CSR fill (both) || cvtX (both). grid 625+20000, blk 256
__global__ __launch_bounds__(256) void k_misc2(const int* __restrict__ ei0, const int* __restrict__ ei1,
                                               const int* __restrict__ rowstart,
                                               int* __restrict__ cursor, int* __restrict__ csr,
                                               const float* __restrict__ x0, const float* __restrict__ x1,
                                               const float* __restrict__ dinv,
                                               _Float16* __restrict__ xs){
  const int bx = blockIdx.x, t = threadIdx.x;
  if (bx < NE_BLK){
    int i = bx*256 + t;
    int br = i >= NEDGES;
    int e  = br ? i - NEDGES : i;
    const int* ei = br ? ei1 : ei0;
    int r = ei[e], c = ei[NEDGES + e];
    int pos = atomicAdd(&cursor[br*NNODES + c], 1);
    csr[br*NEDGES + rowstart[br*(NNODES+1) + c] + pos] = r;
  } else {
    const int idx = bx - NE_BLK;              // 0..19999
    const int br = idx >= NNODES;
    const int row = br ? idx - NNODES : idx;
    const float* x = (br ? x1 : x0) + (size_t)row*FDIM;
    _Float16* o = xs + ((size_t)br*NNODES + row)*FDIM;
    const int f = t*4;
    const float d = dinv[br*NNODES + row];
    const float4 v = *(const float4*)(x + f);
    f16x4 ov;
    ov[0]=(_Float16)(v.x*d); ov[1]=(_Float16)(v.y*d); ov[2]=(_Float16)(v.z*d); ov[3]=(_Float16)(v.w*d);
    *(f16x4*)(o + f) = ov;
  }
}

// gather both branches: grid (NPAD2/2, 2), blk 256 (2 nodes/block)
__global__ __launch_bounds__(256) void k_gath(const _Float16* __restrict__ xs,
                                              const int* __restrict__ rowstart,
                                              const int* __restrict__ csr,
                                              const float* __restrict__ dinv,
                                              _Float16* __restrict__ xa){
  const int t = threadIdx.x;
  const int n = blockIdx.x*2 + (t >> 7);
  gather_body(n, blockIdx.y, t & 127, xs, rowstart, csr, dinv, xa);
}

// GEMM + fused pooling. grid 1280 (= 8*160 XCD-local bijection), blk 256.
// R7-proven 2-buffer counted-vmcnt schedule, 128x128 tile, BK=32.
// Epilogue: write lrelu(acc+bias) tile into the dead 32KB As/Bs LDS (f16),
// then per-column batch-segment sums -> atomicAdd into pool_sum (f32).
__global__ __launch_bounds__(256) void k_gemm(const _Float16* __restrict__ A_,
                                              const _Float16* __restrict__ Bt_,
                                              const float* __restrict__ bg0,
                                              const float* __restrict__ bg1,
                                              const int* __restrict__ bstart_,
                                              float* __restrict__ pool_){
  __shared__ _Float16 smem[16384];   // As[2]:0..8191, Bs[2]:8192..16383; scratch = all 16384
  const int id  = blockIdx.x;                 // 0..1279
  const int w   = (id & 7)*160 + (id >> 3);   // XCD-local bijection
  const int col = w & 7;
  const int ru  = w >> 3;                     // 0..159
  const int row = ru % 80;
  const int br  = ru / 80;

  const _Float16* A  = A_  + (size_t)br*NPAD2*FDIM;
  const _Float16* Bt = Bt_ + (size_t)br*FDIM*FDIM;
  const float* bg = br ? bg1 : bg0;
  const int* bstart = bstart_ + br*(BGR+1);
  float* pool = pool_ + br*BGR*FDIM;

  const int row0 = row*128, col0 = col*128;
  const int tid  = threadIdx.x;
  const int lane = tid & 63, wave = tid >> 6;
  const int wm = wave >> 1, wn = wave & 1;
  const int lr = lane >> 2;
  const int ls = lane & 3;

  f32x4 acc[4][4] = {};

  auto stage = [&](int buf, int k0){
    _Float16* Asb = smem + buf*4096;
    _Float16* Bsb = smem + 8192 + buf*4096;
    #pragma unroll
    for (int j = 0; j < 2; ++j){
      const int r0 = wave*32 + j*16;
      const int ra = r0 + lr;
      const int sa = ls ^ ((ra >> 1) & 3);
      __builtin_amdgcn_global_load_lds(
        (const __attribute__((address_space(1))) void*)(A + (size_t)(row0+ra)*FDIM + k0 + sa*8),
        (__attribute__((address_space(3))) void*)(Asb + r0*32), 16, 0, 0);
      __builtin_amdgcn_global_load_lds(
        (const __attribute__((address_space(1))) void*)(Bt + (size_t)(col0+ra)*FDIM + k0 + sa*8),
        (__attribute__((address_space(3))) void*)(Bsb + r0*32), 16, 0, 0);
    }
  };

  auto compute = [&](int buf){
    const _Float16* Asb = smem + buf*4096;
    const _Float16* Bsb = smem + 8192 + buf*4096;
    f16x8 af[4], bf[4];
    const int s = lane >> 4;
    #pragma unroll
    for (int i = 0; i < 4; ++i){
      const int rA = wm*64 + i*16 + (lane&15);
      af[i] = *(const f16x8*)(Asb + rA*32 + (s ^ ((rA>>1)&3))*8);
      const int rB = wn*64 + i*16 + (lane&15);
      bf[i] = *(const f16x8*)(Bsb + rB*32 + (s ^ ((rB>>1)&3))*8);
    }
    #pragma unroll
    for (int mi = 0; mi < 4; ++mi)
      #pragma unroll
      for (int ni = 0; ni < 4; ++ni)
        acc[mi][ni] = __builtin_amdgcn_mfma_f32_16x16x32_f16(af[mi], bf[ni], acc[mi][ni], 0, 0, 0);
  };

  stage(0, 0);
  #pragma unroll 2
  for (int ks = 0; ks < 32; ++ks){
    if (ks < 31){
      stage((ks+1)&1, (ks+1)*32);
      asm volatile("s_waitcnt vmcnt(4)" ::: "memory");
    } else {
      asm volatile("s_waitcnt vmcnt(0)" ::: "memory");
    }
    __builtin_amdgcn_s_barrier();
    compute(ks&1);
    __builtin_amdgcn_s_barrier();
  }
  __syncthreads();   // all LDS reads drained before scratch overwrite

  // write output tile (f16, post bias+lrelu; 0 for pad rows) into scratch
  float bcol[4];
  #pragma unroll
  for (int ni = 0; ni < 4; ++ni) bcol[ni] = bg[col0 + wn*64 + ni*16 + (lane & 15)];
  #pragma unroll
  for (int mi = 0; mi < 4; ++mi){
    #pragma unroll
    for (int j = 0; j < 4; ++j){
      const int lrow = wm*64 + mi*16 + (lane>>4)*4 + j;
      const int valid = (row0 + lrow) < NNODES;
      #pragma unroll
      for (int ni = 0; ni < 4; ++ni){
        const int lcol = wn*64 + ni*16 + (lane & 15);
        smem[lrow*128 + lcol] = valid ? (_Float16)lrelu(acc[mi][ni][j] + bcol[ni]) : (_Float16)0.f;
      }
    }
  }
  __syncthreads();

  // per-column batch-segment sums: thread t owns col c = t&127, half h = t>>7
  {
    const int c = tid & 127, h = tid >> 7;
    const int base = row0 + h*64;
    int rmax = NNODES - base; if (rmax > 64) rmax = 64;
    if (rmax > 0){
      int b = 0;
      while (bstart[b+1] <= base) ++b;
      int bs_next = bstart[b+1];
      float sum = 0.f;
      for (int r = 0; r < rmax; ++r){
        const int grow = base + r;
        while (grow >= bs_next){
          atomicAdd(&pool[b*FDIM + col0 + c], sum);
          sum = 0.f; ++b; bs_next = bstart[b+1];
        }
        sum += (float)smem[(h*64 + r)*128 + c];
      }
      atomicAdd(&pool[b*FDIM + col0 + c], sum);
    }
  }
}

// fused pf GEMV on pool SUMS: x12 = lrelu(dot(pool_sum,W)/cnt + bias); grid (32,2), blk 512
__global__ __launch_bounds__(512) void k_pf(const float* __restrict__ pool_,
                                            const float* __restrict__ W0,
                                            const float* __restrict__ W1,
                                            const float* __restrict__ bias0,
                                            const float* __restrict__ bias1,
                                            const int* __restrict__ bstart_,
                                            float* __restrict__ x12){
  __shared__ float red[512];
  const int br = blockIdx.y, b = blockIdx.x, t = threadIdx.x;
  const int d = t & 127, kq = t >> 7;
  const float* W = (br ? W1 : W0) + (size_t)kq*256*DDIM + d;
  const float* pp = pool_ + (size_t)(br*BGR + b)*FDIM + kq*256;
  float acc = 0.f;
  #pragma unroll 4
  for (int kk = 0; kk < 256; kk += 4){
    const float4 pv = *(const float4*)(pp + kk);
    acc += pv.x * W[(kk  )*DDIM] + pv.y * W[(kk+1)*DDIM]
         + pv.z * W[(kk+2)*DDIM] + pv.w * W[(kk+3)*DDIM];
  }
  red[t] = acc;
  __syncthreads();
  if (t < 128){
    const int* bstart = bstart_ + br*(BGR+1);
    const int cntn = bstart[b+1] - bstart[b];
    const float inv = 1.0f / fmaxf((float)cntn, 1.0f);
    float a = (red[t] + red[t+128] + red[t+256] + red[t+384]) * inv + (br ? bias1 : bias0)[t];
    x12[((size_t)br*BGR + b)*DDIM + t] = lrelu(a);
  }
}

// head: fc1 -> fc2 -> final sigmoid; grid 32, blk 256
__global__ __launch_bounds__(256) void k_head(const float* __restrict__ x12,
                                              const float* __restrict__ Wfc1, const float* __restrict__ bfc1,
                                              const float* __restrict__ Wfc2, const float* __restrict__ bfc2,
                                              const float* __restrict__ m12,
                                              const float* __restrict__ Wout, const float* __restrict__ bout,
                                              float* __restrict__ out){
  __shared__ float xf[256];
  __shared__ float xc[64];
  __shared__ float red[192];
  const int b = blockIdx.x, t = threadIdx.x;
  const float* xin1 = x12 + (size_t)b*DDIM;
  const float* xin2 = x12 + (size_t)(BGR + b)*DDIM;
  float acc = bfc1[t];
  for (int k = 0; k < 128; ++k) acc += xin1[k] * Wfc1[k*256 + t];
  for (int k = 0; k < 128; ++k) acc += xin2[k] * Wfc1[(128+k)*256 + t];
  xf[t] = lrelu(acc);
  __syncthreads();
  if (t < 64){
    float a = bfc2[t];
    for (int k = 0; k < 256; ++k) a += xf[k] * Wfc2[k*64 + t];
    xc[t] = lrelu(a);
  }
  __syncthreads();
  if (t < 192){
    float v;
    if (t < 64)       v = xc[t] * Wout[t];
    else if (t < 128) v = m12[(size_t)b*64 + (t-64)] * Wout[t];
    else              v = m12[(size_t)(BGR + b)*64 + (t-128)] * Wout[t];
    red[t] = v;
  }
  __syncthreads();
  if (t == 0){
    float a = bout[0];
    for (int i = 0; i < 192; ++i) a += red[i];
    out[b] = 1.0f / (1.0f + expf(-a));
  }
}

extern "C" void kernel_launch(void* const* d_in, const int* in_sizes, int n_in,
                              void* d_out, int out_size, void* d_ws, size_t ws_size,
                              hipStream_t stream){
  const float* pro1_x = (const float*)d_in[0];
  const int*   ei1    = (const int*)d_in[1];
  const int*   batch1 = (const int*)d_in[2];
  const float* pro2_x = (const float*)d_in[3];
  const int*   ei2    = (const int*)d_in[4];
  const int*   batch2 = (const int*)d_in[5];
  const float* mas1_s = (const float*)d_in[6];
  const float* mas1_f = (const float*)d_in[7];
  const float* mas2_s = (const float*)d_in[8];
  const float* mas2_f = (const float*)d_in[9];
  const float* W_g1 = (const float*)d_in[10]; const float* b_g1 = (const float*)d_in[11];
  const float* W_g2 = (const float*)d_in[12]; const float* b_g2 = (const float*)d_in[13];
  const float* W_pf1= (const float*)d_in[14]; const float* b_pf1= (const float*)d_in[15];
  const float* W_pf2= (const float*)d_in[16]; const float* b_pf2= (const float*)d_in[17];
  const float* W_fc1= (const float*)d_in[18]; const float* b_fc1= (const float*)d_in[19];
  const float* W_fc2= (const float*)d_in[20]; const float* b_fc2= (const float*)d_in[21];
  const float* cs1w = (const float*)d_in[22]; const float* cs1b = (const float*)d_in[23];
  const float* cf1w = (const float*)d_in[24]; const float* cf1b = (const float*)d_in[25];
  const float* cs2w = (const float*)d_in[26]; const float* cs2b = (const float*)d_in[27];
  const float* cf2w = (const float*)d_in[28]; const float* cf2b = (const float*)d_in[29];
  const float* W_m1 = (const float*)d_in[30]; const float* b_m1 = (const float*)d_in[31];
  const float* W_m2 = (const float*)d_in[32]; const float* b_m2 = (const float*)d_in[33];
  const float* W_out= (const float*)d_in[34]; const float* b_out= (const float*)d_in[35];
  float* out = (float*)d_out;
  (void)in_sizes; (void)n_in; (void)out_size; (void)ws_size;

  char* p = (char*)d_ws;
  auto alloc = [&](size_t bytes)->char*{ char* r = p; p += (bytes + 255) & ~(size_t)255; return r; };
  int*   cntcur = (int*)alloc((size_t)4*NNODES*4);   // cnt, cursor (zeroed)
  float* pool   = (float*)alloc((size_t)2*BGR*FDIM*4); // pool sums (zeroed, adjacent)
  int*   cnt    = cntcur;
  int*   cursor = cntcur + 2*NNODES;
  _Float16* xs  = (_Float16*)alloc((size_t)2*NNODES*FDIM*2);
  _Float16* xa  = (_Float16*)alloc((size_t)2*NPAD2*FDIM*2);
  _Float16* Wtb = (_Float16*)alloc((size_t)2*FDIM*FDIM*2);
  float* dinv = (float*)alloc((size_t)2*NNODES*4);
  int*   rowstart = (int*)alloc((size_t)2*(NNODES+1)*4);
  int*   csr  = (int*)alloc((size_t)2*NEDGES*4);
  int*   bstart = (int*)alloc((size_t)2*(BGR+1)*4);
  float* x12  = (float*)alloc((size_t)2*BGR*DDIM*4);
  float* m12  = (float*)alloc((size_t)2*BGR*64*4);

  // zero cnt+cursor+pool in one DMA (they are adjacent in the arena)
  hipMemsetAsync(cntcur, 0, (size_t)4*NNODES*4 + (size_t)2*BGR*FDIM*4, stream);
  k_misc1<<<NE_BLK + 2048 + 64, 256, 0, stream>>>(ei1, ei2, cnt, W_g1, W_g2, Wtb,
                                                  mas1_s, mas1_f, mas2_s, mas2_f,
                                                  cs1w, cs1b, cf1w, cf1b,
                                                  cs2w, cs2b, cf2w, cf2b,
                                                  W_m1, b_m1, W_m2, b_m2, m12);
  k_scan<<<2, 1024, 0, stream>>>(cnt, rowstart, dinv, batch1, batch2, bstart);
  k_misc2<<<NE_BLK + 2*NNODES, 256, 0, stream>>>(ei1, ei2, rowstart, cursor, csr,
                                                 pro1_x, pro2_x, dinv, xs);
  k_gath<<<dim3(NPAD2/2, 2), 256, 0, stream>>>(xs, rowstart, csr, dinv, xa);
  k_gemm<<<1280, 256, 0, stream>>>(xa, Wtb, b_g1, b_g2, bstart, pool);
  k_pf<<<dim3(BGR, 2), 512, 0, stream>>>(pool, W_pf1, W_pf2, b_pf1, b_pf2, bstart, x12);
  k_head<<<BGR, 256, 0, stream>>>(x12, W_fc1, b_fc1, W_fc2, b_fc2, m12, W_out, b_out, out);
}